// Round 1
// baseline (77.382 us; speedup 1.0000x reference)
//
#include <hip/hip_runtime.h>

#define CUT_SIZE 224
#define SIDE 1024
#define CUTN 128

// One thread computes 4 consecutive output x-pixels (float4 store).
// Grid: x = 224*56/256 = 49 blocks of 256 threads, y = channel (3), z = cutout (128).
__global__ __launch_bounds__(256) void make_cutouts_kernel(
    const float* __restrict__ img,     // [3, 1024, 1024]
    const int* __restrict__ sizes,     // [128]
    const int* __restrict__ offy,      // [128]
    const int* __restrict__ offx,      // [128]
    float* __restrict__ out)           // [128, 3, 224, 224]
{
    const int n = blockIdx.z;
    const int c = blockIdx.y;
    const int pix = blockIdx.x * blockDim.x + threadIdx.x;  // 0 .. 224*56-1
    const int y  = pix / 56;     // output row
    const int xg = pix % 56;     // group of 4 output cols

    const float scale = (float)sizes[n] * (1.0f / (float)CUT_SIZE);
    const float oy = (float)offy[n];
    const float ox = (float)offx[n];

    // y coordinate (align_corners=False): ys = oy + (y+0.5)*scale - 0.5, clipped
    float fy = fmaf((float)y + 0.5f, scale, oy - 0.5f);
    fy = fminf(fmaxf(fy, 0.0f), (float)(SIDE - 1));
    const int   y0 = (int)fy;
    const int   y1 = min(y0 + 1, SIDE - 1);
    const float wy = fy - (float)y0;

    const float* __restrict__ row0 = img + (size_t)c * (SIDE * SIDE) + (size_t)y0 * SIDE;
    const float* __restrict__ row1 = img + (size_t)c * (SIDE * SIDE) + (size_t)y1 * SIDE;

    float4 o;
    float* op = &o.x;
#pragma unroll
    for (int j = 0; j < 4; ++j) {
        const float xf = (float)(xg * 4 + j);
        float fx = fmaf(xf + 0.5f, scale, ox - 0.5f);
        fx = fminf(fmaxf(fx, 0.0f), (float)(SIDE - 1));
        const int   x0 = (int)fx;
        const int   x1 = min(x0 + 1, SIDE - 1);
        const float wx = fx - (float)x0;

        // Same order as reference: interpolate along y first, then x.
        const float a = row0[x0] * (1.0f - wy) + row1[x0] * wy;
        const float b = row0[x1] * (1.0f - wy) + row1[x1] * wy;
        float v = a * (1.0f - wx) + b * wx;
        v = fminf(fmaxf(v, 0.0f), 1.0f);   // ClampWithGrad forward
        op[j] = v;
    }

    const size_t obase = ((((size_t)n * 3 + c) * CUT_SIZE) + y) * CUT_SIZE + (size_t)xg * 4;
    *reinterpret_cast<float4*>(out + obase) = o;
}

extern "C" void kernel_launch(void* const* d_in, const int* in_sizes, int n_in,
                              void* d_out, int out_size, void* d_ws, size_t ws_size,
                              hipStream_t stream) {
    const float* img   = (const float*)d_in[0];
    const int*   sizes = (const int*)d_in[1];
    const int*   offy  = (const int*)d_in[2];
    const int*   offx  = (const int*)d_in[3];
    float*       out   = (float*)d_out;

    dim3 grid(49, 3, CUTN);   // 49*256 = 12544 = 224 rows * 56 groups
    dim3 block(256, 1, 1);
    make_cutouts_kernel<<<grid, block, 0, stream>>>(img, sizes, offy, offx, out);
}

// Round 2
// 61.359 us; speedup vs baseline: 1.2611x; 1.2611x over previous
//
#include <hip/hip_runtime.h>

#define CUT_SIZE 224
#define SIDE 1024
#define CUTN 128
#define LDSW 1036   // floats per staged row (max span ~1026 incl. 16B alignment slack)

// One wave per output row: stage rows y0,y1 in LDS (coalesced float4 loads),
// then bilinear-gather from LDS. 4 waves (4 rows) per block.
// Grid: x = 56 row-groups, y = channel (3), z = cutout (128).
__global__ __launch_bounds__(256) void make_cutouts_kernel(
    const float* __restrict__ img,     // [3, 1024, 1024]
    const int* __restrict__ sizes,     // [128]
    const int* __restrict__ offy,      // [128]
    const int* __restrict__ offx,      // [128]
    float* __restrict__ out)           // [128, 3, 224, 224]
{
    __shared__ float lds[8][LDSW];

    const int n    = blockIdx.z;
    const int c    = blockIdx.y;
    const int w    = threadIdx.x >> 6;     // wave id 0..3
    const int lane = threadIdx.x & 63;
    const int y    = blockIdx.x * 4 + w;   // output row 0..223

    const float scale = (float)sizes[n] * (1.0f / (float)CUT_SIZE);
    const float oy = (float)offy[n];
    const float ox = (float)offx[n];

    // y coordinate (align_corners=False), clipped
    float fy = fmaf((float)y + 0.5f, scale, oy - 0.5f);
    fy = fminf(fmaxf(fy, 0.0f), (float)(SIDE - 1));
    const int   y0 = (int)fy;
    const int   y1 = min(y0 + 1, SIDE - 1);
    const float wy = fy - (float)y0;

    // x span needed by this row (wave-uniform)
    float fx0 = fmaf(0.5f, scale, ox - 0.5f);
    fx0 = fminf(fmaxf(fx0, 0.0f), (float)(SIDE - 1));
    float fxl = fmaf((float)CUT_SIZE - 0.5f, scale, ox - 0.5f);
    fxl = fminf(fmaxf(fxl, 0.0f), (float)(SIDE - 1));
    const int xb  = (int)fx0;
    const int xe  = min((int)fxl + 1, SIDE - 1);   // inclusive last needed col
    const int xb4 = xb & ~3;                       // 16B-aligned load base

    // Stage the two input rows into this wave's LDS slice (coalesced float4).
    // Loads never cross the row end: xb4+4i <= xe <= 1023 and xb4+4i is 4-aligned
    // so the float4 covers at most cols ..1023.
    const float4* __restrict__ rp0 =
        reinterpret_cast<const float4*>(img + (size_t)c * (SIDE * SIDE) + (size_t)y0 * SIDE + xb4);
    const float4* __restrict__ rp1 =
        reinterpret_cast<const float4*>(img + (size_t)c * (SIDE * SIDE) + (size_t)y1 * SIDE + xb4);
    float* __restrict__ l0 = lds[2 * w];
    float* __restrict__ l1 = lds[2 * w + 1];
    const int nf4 = ((xe - xb4) >> 2) + 1;         // number of float4s (wave-uniform)
    for (int i = lane; i < nf4; i += 64) {
        *reinterpret_cast<float4*>(l0 + 4 * i) = rp0[i];
        *reinterpret_cast<float4*>(l1 + 4 * i) = rp1[i];
    }
    __syncthreads();   // cross-lane LDS visibility (waves are balanced; one barrier total)

    const float wy0 = 1.0f - wy;
    const size_t obase = ((((size_t)n * 3 + c) * CUT_SIZE) + y) * CUT_SIZE;

#pragma unroll
    for (int it = 0; it < 4; ++it) {
        const int p = lane + it * 64;              // output col
        if (p < CUT_SIZE) {
            float fx = fmaf((float)p + 0.5f, scale, ox - 0.5f);
            fx = fminf(fmaxf(fx, 0.0f), (float)(SIDE - 1));
            const int   x0 = (int)fx;
            const int   x1 = min(x0 + 1, SIDE - 1);
            const float wx = fx - (float)x0;
            const int i0 = x0 - xb4;
            const int i1 = x1 - xb4;
            // y-lerp then x-lerp (same as reference's separable form)
            const float a = l0[i0] * wy0 + l1[i0] * wy;
            const float b = l0[i1] * wy0 + l1[i1] * wy;
            float v = a * (1.0f - wx) + b * wx;
            v = fminf(fmaxf(v, 0.0f), 1.0f);
            out[obase + p] = v;
        }
    }
}

extern "C" void kernel_launch(void* const* d_in, const int* in_sizes, int n_in,
                              void* d_out, int out_size, void* d_ws, size_t ws_size,
                              hipStream_t stream) {
    const float* img   = (const float*)d_in[0];
    const int*   sizes = (const int*)d_in[1];
    const int*   offy  = (const int*)d_in[2];
    const int*   offx  = (const int*)d_in[3];
    float*       out   = (float*)d_out;

    dim3 grid(CUT_SIZE / 4, 3, CUTN);   // 56 x 3 x 128
    dim3 block(256, 1, 1);
    make_cutouts_kernel<<<grid, block, 0, stream>>>(img, sizes, offy, offx, out);
}

// Round 3
// 58.964 us; speedup vs baseline: 1.3124x; 1.0406x over previous
//
#include <hip/hip_runtime.h>

#define CUT_SIZE 224
#define SIDE 1024
#define CUTN 128
#define LDSW 1040   // floats per blended row (max span ~1026 + alignment slack)

// One wave per output row. Stage = load rows y0,y1 (coalesced float4),
// y-lerp IN REGISTERS, write one blended row to LDS. Then x-gather from LDS.
// 4 waves (4 output rows) per block; 16.6 KB LDS -> 8 blocks/CU.
__global__ __launch_bounds__(256) void make_cutouts_kernel(
    const float* __restrict__ img,     // [3, 1024, 1024]
    const int* __restrict__ sizes,     // [128]
    const int* __restrict__ offy,      // [128]
    const int* __restrict__ offx,      // [128]
    float* __restrict__ out)           // [128, 3, 224, 224]
{
    __shared__ float lds[4][LDSW];

    const int n    = blockIdx.z;
    const int c    = blockIdx.y;
    const int w    = threadIdx.x >> 6;     // wave id 0..3
    const int lane = threadIdx.x & 63;
    const int y    = blockIdx.x * 4 + w;   // output row 0..223

    const float scale = (float)sizes[n] * (1.0f / (float)CUT_SIZE);
    const float oy = (float)offy[n];
    const float ox = (float)offx[n];

    // y coordinate (align_corners=False), clipped
    float fy = fmaf((float)y + 0.5f, scale, oy - 0.5f);
    fy = fminf(fmaxf(fy, 0.0f), (float)(SIDE - 1));
    const int   y0 = (int)fy;
    const int   y1 = min(y0 + 1, SIDE - 1);
    const float wy  = fy - (float)y0;
    const float wy0 = 1.0f - wy;

    // x span needed by this row (wave-uniform: same size for all rows of cutout n)
    float fx0 = fmaf(0.5f, scale, ox - 0.5f);
    fx0 = fminf(fmaxf(fx0, 0.0f), (float)(SIDE - 1));
    float fxl = fmaf((float)CUT_SIZE - 0.5f, scale, ox - 0.5f);
    fxl = fminf(fmaxf(fxl, 0.0f), (float)(SIDE - 1));
    const int xb  = (int)fx0;
    const int xe  = min((int)fxl + 1, SIDE - 1);   // inclusive last needed col
    const int xb4 = xb & ~3;                       // 16B-aligned load base

    // Stage: load both rows, y-lerp in registers, write ONE row to LDS.
    const float4* __restrict__ rp0 =
        reinterpret_cast<const float4*>(img + (size_t)c * (SIDE * SIDE) + (size_t)y0 * SIDE + xb4);
    const float4* __restrict__ rp1 =
        reinterpret_cast<const float4*>(img + (size_t)c * (SIDE * SIDE) + (size_t)y1 * SIDE + xb4);
    float* __restrict__ l = lds[w];
    const int nf4 = ((xe - xb4) >> 2) + 1;         // number of float4s (wave-uniform)
    for (int i = lane; i < nf4; i += 64) {
        const float4 a = rp0[i];
        const float4 b = rp1[i];
        float4 r;
        r.x = a.x * wy0 + b.x * wy;
        r.y = a.y * wy0 + b.y * wy;
        r.z = a.z * wy0 + b.z * wy;
        r.w = a.w * wy0 + b.w * wy;
        *reinterpret_cast<float4*>(l + 4 * i) = r;
    }
    __syncthreads();   // waves are balanced (same span); one barrier total

    const size_t obase = ((((size_t)n * 3 + c) * CUT_SIZE) + y) * CUT_SIZE;
    const int ilast = xe - xb4;                    // last valid LDS index

#pragma unroll
    for (int it = 0; it < 4; ++it) {
        const int p = lane + it * 64;              // output col
        if (p < CUT_SIZE) {
            float fx = fmaf((float)p + 0.5f, scale, ox - 0.5f);
            fx = fminf(fmaxf(fx, 0.0f), (float)(SIDE - 1));
            // move to LDS-local coordinates (fx >= xb >= xb4)
            const float fl = fx - (float)xb4;
            const int   i0 = (int)fl;
            const int   i1 = min(i0 + 1, ilast);
            const float wx = fl - (float)i0;
            const float a = l[i0];
            const float b = l[i1];
            float v = a * (1.0f - wx) + b * wx;
            v = fminf(fmaxf(v, 0.0f), 1.0f);
            out[obase + p] = v;
        }
    }
}

extern "C" void kernel_launch(void* const* d_in, const int* in_sizes, int n_in,
                              void* d_out, int out_size, void* d_ws, size_t ws_size,
                              hipStream_t stream) {
    const float* img   = (const float*)d_in[0];
    const int*   sizes = (const int*)d_in[1];
    const int*   offy  = (const int*)d_in[2];
    const int*   offx  = (const int*)d_in[3];
    float*       out   = (float*)d_out;

    dim3 grid(CUT_SIZE / 4, 3, CUTN);   // 56 x 3 x 128
    dim3 block(256, 1, 1);
    make_cutouts_kernel<<<grid, block, 0, stream>>>(img, sizes, offy, offx, out);
}

// Round 4
// 58.212 us; speedup vs baseline: 1.3293x; 1.0129x over previous
//
#include <hip/hip_runtime.h>

#define CUT_SIZE 224
#define SIDE 1024
#define CUTN 128
#define LDSW 1032   // floats per blended row (max needed 1024) + slack

// One wave per output row, ALL 3 channels. x-mapping (i0,i1,wx) computed once
// into registers, reused per channel. LDS row is WAVE-PRIVATE (no __syncthreads;
// per-wave DS ordering + s_waitcnt lgkmcnt(0) gives cross-lane visibility).
// 2 waves per 128-thread block, 8.3 KB LDS -> 16 blocks/CU -> 32 waves/CU cap.
__global__ __launch_bounds__(128) void make_cutouts_kernel(
    const float* __restrict__ img,     // [3, 1024, 1024]
    const int* __restrict__ sizes,     // [128]
    const int* __restrict__ offy,      // [128]
    const int* __restrict__ offx,      // [128]
    float* __restrict__ out)           // [128, 3, 224, 224]
{
    __shared__ float lds[2][LDSW];

    const int n    = blockIdx.y;
    const int w    = threadIdx.x >> 6;     // wave id 0..1
    const int lane = threadIdx.x & 63;
    const int y    = blockIdx.x * 2 + w;   // output row 0..223

    const float scale = (float)sizes[n] * (1.0f / (float)CUT_SIZE);
    const float oy = (float)offy[n];
    const float ox = (float)offx[n];

    // y coordinate (align_corners=False), clipped
    float fy = fmaf((float)y + 0.5f, scale, oy - 0.5f);
    fy = fminf(fmaxf(fy, 0.0f), (float)(SIDE - 1));
    const int   y0 = (int)fy;
    const int   y1 = min(y0 + 1, SIDE - 1);
    const float wy  = fy - (float)y0;
    const float wy0 = 1.0f - wy;

    // x span needed by this row (wave-uniform, same for all rows of cutout n)
    float fx0 = fmaf(0.5f, scale, ox - 0.5f);
    fx0 = fminf(fmaxf(fx0, 0.0f), (float)(SIDE - 1));
    float fxl = fmaf((float)CUT_SIZE - 0.5f, scale, ox - 0.5f);
    fxl = fminf(fmaxf(fxl, 0.0f), (float)(SIDE - 1));
    const int xb    = (int)fx0;
    const int xe    = min((int)fxl + 1, SIDE - 1);  // inclusive last needed col
    const int xb4   = xb & ~3;                      // 16B-aligned load base
    const int ilast = xe - xb4;                     // last valid LDS index
    const int nf4   = (ilast >> 2) + 1;             // float4 count (wave-uniform)

    // Precompute x-mapping ONCE (reused for all 3 channels).
    int   i0r[4], i1r[4];
    float wxr[4], wx0r[4];
#pragma unroll
    for (int it = 0; it < 4; ++it) {
        const int p = min(lane + it * 64, CUT_SIZE - 1);   // clamp; stores guarded below
        float fx = fmaf((float)p + 0.5f, scale, ox - 0.5f);
        fx = fminf(fmaxf(fx, 0.0f), (float)(SIDE - 1));
        const float fl = fx - (float)xb4;                  // fx >= xb >= xb4
        const int   i0 = (int)fl;
        i0r[it]  = i0;
        i1r[it]  = min(i0 + 1, ilast);
        wxr[it]  = fl - (float)i0;
        wx0r[it] = 1.0f - wxr[it];
    }

    const int r0off = y0 * SIDE + xb4;
    const int r1off = y1 * SIDE + xb4;
    float* __restrict__ l = lds[w];
    const size_t obase0 = (((size_t)n * 3) * CUT_SIZE + y) * CUT_SIZE;

    for (int c = 0; c < 3; ++c) {
        const float* __restrict__ ch = img + (size_t)c * (SIDE * SIDE);
        const float4* __restrict__ rp0 = reinterpret_cast<const float4*>(ch + r0off);
        const float4* __restrict__ rp1 = reinterpret_cast<const float4*>(ch + r1off);

        // Stage: load both input rows, y-lerp in registers, write blended row.
        // Last chunk base = xb4+4i is 4-aligned and <= 1023 => <= 1020: never OOB.
        for (int i = lane; i < nf4; i += 64) {
            const float4 a = rp0[i];
            const float4 b = rp1[i];
            float4 r;
            r.x = a.x * wy0 + b.x * wy;
            r.y = a.y * wy0 + b.y * wy;
            r.z = a.z * wy0 + b.z * wy;
            r.w = a.w * wy0 + b.w * wy;
            *reinterpret_cast<float4*>(l + 4 * i) = r;
        }
        // Wave-private LDS: per-wave DS ops complete in order; drain them so all
        // lanes' writes are visible. "memory" clobber stops compiler reordering.
        asm volatile("s_waitcnt lgkmcnt(0)" ::: "memory");

        const size_t obase = obase0 + (size_t)c * (CUT_SIZE * CUT_SIZE);
#pragma unroll
        for (int it = 0; it < 4; ++it) {
            const int p = lane + it * 64;
            if (p < CUT_SIZE) {
                const float a = l[i0r[it]];
                const float b = l[i1r[it]];
                float v = a * wx0r[it] + b * wxr[it];
                v = fminf(fmaxf(v, 0.0f), 1.0f);
                out[obase + p] = v;
            }
        }
        // Order: next channel's ds_writes must not pass this channel's ds_reads.
        asm volatile("" ::: "memory");
    }
}

extern "C" void kernel_launch(void* const* d_in, const int* in_sizes, int n_in,
                              void* d_out, int out_size, void* d_ws, size_t ws_size,
                              hipStream_t stream) {
    const float* img   = (const float*)d_in[0];
    const int*   sizes = (const int*)d_in[1];
    const int*   offy  = (const int*)d_in[2];
    const int*   offx  = (const int*)d_in[3];
    float*       out   = (float*)d_out;

    dim3 grid(CUT_SIZE / 2, CUTN);   // 112 x 128 blocks; block = 2 waves = 2 rows
    dim3 block(128, 1, 1);
    make_cutouts_kernel<<<grid, block, 0, stream>>>(img, sizes, offy, offx, out);
}